// Round 5
// baseline (131.201 us; speedup 1.0000x reference)
//
#include <hip/hip_runtime.h>

typedef unsigned short u16;
typedef short bf16x8 __attribute__((ext_vector_type(8)));
typedef float f32x4 __attribute__((ext_vector_type(4)));

#define BB 8
#define CC 768
#define NN 256
#define HH 12
#define DD 64
#define K3 3072          // H*N
#define BCN 196608       // C*N per batch
#define SCALE 0.125f
#define LDP 72           // LDS pitch (u16) for K=64 rows: 144B, 16B-aligned, 2-way banks
#define LDP2 152         // LDS pitch (u16) for K=128 rows: 304B, 16B-aligned, 2-way banks
#define TP 72            // T pitch (u16): bf16 cross tile [128][64]

__device__ __forceinline__ u16 f2b(float f) {
    union { float f; unsigned int i; } v; v.f = f;
    unsigned int r = v.i + 0x7FFFu + ((v.i >> 16) & 1u);
    return (u16)(r >> 16);
}

// 64x64x64 MFMA macro-step, pitch LDP (K=64 kernels)
#define MFMA8(ASP, BSP, ACC)                                                              \
    _Pragma("unroll")                                                                     \
    for (int kk = 0; kk < 2; ++kk) {                                                      \
        bf16x8 a0 = *reinterpret_cast<bf16x8*>((ASP) + (wm + tx) * LDP + kk * 32 + q * 8);\
        bf16x8 a1 = *reinterpret_cast<bf16x8*>((ASP) + (wm + 16 + tx) * LDP + kk * 32 + q * 8);\
        bf16x8 b0 = *reinterpret_cast<bf16x8*>((BSP) + (wn + tx) * LDP + kk * 32 + q * 8);\
        bf16x8 b1 = *reinterpret_cast<bf16x8*>((BSP) + (wn + 16 + tx) * LDP + kk * 32 + q * 8);\
        ACC[0][0] = __builtin_amdgcn_mfma_f32_16x16x32_bf16(a0, b0, ACC[0][0], 0, 0, 0);  \
        ACC[0][1] = __builtin_amdgcn_mfma_f32_16x16x32_bf16(a0, b1, ACC[0][1], 0, 0, 0);  \
        ACC[1][0] = __builtin_amdgcn_mfma_f32_16x16x32_bf16(a1, b0, ACC[1][0], 0, 0, 0);  \
        ACC[1][1] = __builtin_amdgcn_mfma_f32_16x16x32_bf16(a1, b1, ACC[1][1], 0, 0, 0);  \
    }

// 64x64x128 MFMA macro-step, pitch LDP2 (K=128 kernels)
#define MFMA16(ASP, BSP, ACC)                                                             \
    _Pragma("unroll")                                                                     \
    for (int kk = 0; kk < 4; ++kk) {                                                      \
        bf16x8 a0 = *reinterpret_cast<bf16x8*>((ASP) + (wm + tx) * LDP2 + kk * 32 + q * 8);\
        bf16x8 a1 = *reinterpret_cast<bf16x8*>((ASP) + (wm + 16 + tx) * LDP2 + kk * 32 + q * 8);\
        bf16x8 b0 = *reinterpret_cast<bf16x8*>((BSP) + (wn + tx) * LDP2 + kk * 32 + q * 8);\
        bf16x8 b1 = *reinterpret_cast<bf16x8*>((BSP) + (wn + 16 + tx) * LDP2 + kk * 32 + q * 8);\
        ACC[0][0] = __builtin_amdgcn_mfma_f32_16x16x32_bf16(a0, b0, ACC[0][0], 0, 0, 0);  \
        ACC[0][1] = __builtin_amdgcn_mfma_f32_16x16x32_bf16(a0, b1, ACC[0][1], 0, 0, 0);  \
        ACC[1][0] = __builtin_amdgcn_mfma_f32_16x16x32_bf16(a1, b0, ACC[1][0], 0, 0, 0);  \
        ACC[1][1] = __builtin_amdgcn_mfma_f32_16x16x32_bf16(a1, b1, ACC[1][1], 0, 0, 0);  \
    }

// ---------------------------------------------------------------------------
// Stage 1: cp[b,o,n] = sum_c Wp[o,c]*cross[b,c,n] + bp[o]     (bf16 out)
// K=128 per iter (6 iters), 1-deep register prefetch. cross is converted to
// bf16 BEFORE staging T (same f2b rounding point -> numerics unchanged), so
// the [128][64] T tile fits LDS. Blocks (0,0,b) zero G[b] for k_gram.
// ---------------------------------------------------------------------------
__global__ __launch_bounds__(256) void k_proj(
    const float* __restrict__ Wp, const float* __restrict__ cross,
    const float* __restrict__ bp, u16* __restrict__ cp, float* __restrict__ G)
{
    __shared__ __align__(16) u16 As[64 * LDP2];   // 19456 B
    __shared__ __align__(16) u16 Bs[64 * LDP2];   // 19456 B
    __shared__ __align__(16) u16 T[128 * TP];     // 18432 B   (total 56 KB)
    const int n0 = blockIdx.x * 64;
    const int o0 = blockIdx.y * 64;
    const int b  = blockIdx.z;
    const int t = threadIdx.x;
    const int lane = t & 63, wave = t >> 6;
    const int q = lane >> 4, tx = lane & 15;
    const int wm = (wave & 1) * 32, wn = (wave >> 1) * 32;
    const int r4 = t >> 2, cq = t & 3;      // A staging: row, col-quarter
    const int rT = t >> 1, hT = t & 1;      // T staging: row (128), n-half

    if (blockIdx.x == 0 && blockIdx.y == 0) {   // zero G[b]
        float4 z = {0.f, 0.f, 0.f, 0.f};
        float* Gb = G + b * 4096;
        #pragma unroll
        for (int j = 0; j < 4; ++j)
            *reinterpret_cast<float4*>(Gb + t * 4 + j * 1024) = z;
    }

    const float* crb = cross + b * BCN;
    const float* wsrc = Wp + (o0 + r4) * CC;

    f32x4 acc[2][2] = {};
    float4 ra[8], rc[8];
    #pragma unroll
    for (int u = 0; u < 8; ++u) {               // prologue: iter-0 tiles -> regs
        ra[u] = *reinterpret_cast<const float4*>(wsrc + (cq + 4 * u) * 4);
        rc[u] = *reinterpret_cast<const float4*>(crb + rT * NN + n0 + hT * 32 + u * 4);
    }
    for (int it = 0; it < 6; ++it) {
        if (it > 0) __syncthreads();            // prev MFMA readers done
        {   // regs -> As (cvt) and T (cvt)
            u16* dstA = As + r4 * LDP2;
            #pragma unroll
            for (int u = 0; u < 8; ++u) {
                const int cl = (cq + 4 * u) * 4;
                ushort4 w; w.x = f2b(ra[u].x); w.y = f2b(ra[u].y);
                w.z = f2b(ra[u].z); w.w = f2b(ra[u].w);
                *reinterpret_cast<ushort4*>(dstA + cl) = w;
            }
            u16* dstT = T + rT * TP + hT * 32;
            #pragma unroll
            for (int u = 0; u < 8; ++u) {
                ushort4 w; w.x = f2b(rc[u].x); w.y = f2b(rc[u].y);
                w.z = f2b(rc[u].z); w.w = f2b(rc[u].w);
                *reinterpret_cast<ushort4*>(dstT + u * 4) = w;
            }
        }
        if (it < 5) {   // next-iter loads in flight across transpose + MFMA
            const int c0 = (it + 1) * 128;
            #pragma unroll
            for (int u = 0; u < 8; ++u) {
                ra[u] = *reinterpret_cast<const float4*>(wsrc + c0 + (cq + 4 * u) * 4);
                rc[u] = *reinterpret_cast<const float4*>(crb + (c0 + rT) * NN + n0 + hT * 32 + u * 4);
            }
        }
        __syncthreads();
        {   // Bs[n][c] = T[c][n]  (u16 transpose; col reads ~2-way = free)
            const int nn = t >> 2, dq = t & 3;
            u16* dst = Bs + nn * LDP2;
            #pragma unroll
            for (int u = 0; u < 8; ++u) {
                const int c4 = (dq + 4 * u) * 4;
                ushort4 w;
                w.x = T[(c4 + 0) * TP + nn]; w.y = T[(c4 + 1) * TP + nn];
                w.z = T[(c4 + 2) * TP + nn]; w.w = T[(c4 + 3) * TP + nn];
                *reinterpret_cast<ushort4*>(dst + c4) = w;
            }
        }
        __syncthreads();
        MFMA16(As, Bs, acc)
    }
    u16* cpb = cp + b * BCN;
    #pragma unroll
    for (int i = 0; i < 2; ++i)
        #pragma unroll
        for (int j = 0; j < 2; ++j)
            #pragma unroll
            for (int r = 0; r < 4; ++r) {
                const int o = o0 + wm + i * 16 + q * 4 + r;
                const int n = n0 + wn + j * 16 + tx;
                cpb[o * NN + n] = f2b(acc[i][j][r] + bp[o]);
            }
}

// ---------------------------------------------------------------------------
// Stage 2: G[b][dd][d] += SCALE * sum_k cross_view[dd][k]*cp_view[d][k]
// Split-K 24 x 128 chunks (K=128 per block -> half the blocks AND half the
// G atomic traffic vs K=64). 192 blocks, all single-resident.
// ---------------------------------------------------------------------------
__global__ __launch_bounds__(256) void k_gram(
    const float* __restrict__ cross, const u16* __restrict__ cp, float* __restrict__ G)
{
    __shared__ __align__(16) u16 As[64 * LDP2];
    __shared__ __align__(16) u16 Bs[64 * LDP2];
    const int kb = blockIdx.x * 128;
    const int b  = blockIdx.y;
    const int t = threadIdx.x;
    const int lane = t & 63, wave = t >> 6;
    const int q = lane >> 4, tx = lane & 15;
    const int wm = (wave & 1) * 32, wn = (wave >> 1) * 32;
    const int r4 = t >> 2, cq = t & 3;
    const float* crb = cross + b * BCN;
    const u16* cpb = cp + b * BCN;
    f32x4 acc[2][2] = {};
    {   // As[dd][k] = cvt(crossflat[dd][kb+k])
        const float* src = crb + r4 * K3 + kb;
        u16* dst = As + r4 * LDP2;
        #pragma unroll
        for (int u = 0; u < 8; ++u) {
            const int cl = (cq + 4 * u) * 4;
            float4 v = *reinterpret_cast<const float4*>(src + cl);
            ushort4 w; w.x = f2b(v.x); w.y = f2b(v.y); w.z = f2b(v.z); w.w = f2b(v.w);
            *reinterpret_cast<ushort4*>(dst + cl) = w;
        }
    }
    {   // Bs[d][k] = cpflat[d][kb+k]  (bf16 passthrough)
        const u16* src = cpb + r4 * K3 + kb;
        u16* dst = Bs + r4 * LDP2;
        #pragma unroll
        for (int u = 0; u < 4; ++u) {
            const int ch = ((t & 3) + 4 * u) * 8;
            *reinterpret_cast<uint4*>(dst + ch) = *reinterpret_cast<const uint4*>(src + ch);
        }
    }
    __syncthreads();
    MFMA16(As, Bs, acc)
    float* Gb = G + b * 4096;
    #pragma unroll
    for (int i = 0; i < 2; ++i)
        #pragma unroll
        for (int j = 0; j < 2; ++j)
            #pragma unroll
            for (int r = 0; r < 4; ++r) {
                const int dd = wm + i * 16 + q * 4 + r;
                const int d  = wn + j * 16 + tx;
                atomicAdd(Gb + dd * DD + d, acc[i][j][r] * SCALE);
            }
}

// ---------------------------------------------------------------------------
// Stage 3: U[b][m][dd] = sum_d xT[m][d]*G[dd][d].  Single K=64 iter; unchanged.
// U (bf16) aliases cp. 48 m-tiles x 8 batches.
// ---------------------------------------------------------------------------
__global__ __launch_bounds__(256) void k_xm(
    const float* __restrict__ x, const float* __restrict__ G, u16* __restrict__ U)
{
    __shared__ __align__(16) u16 As[64 * LDP];
    __shared__ __align__(16) u16 Bs[64 * LDP];
    __shared__ __align__(16) float T[64][68];
    const int m0 = blockIdx.x * 64;
    const int b  = blockIdx.y;
    const int h   = m0 >> 8;       // head index (m = h*256 + nn)
    const int nn0 = m0 & 255;
    const int t = threadIdx.x;
    const int lane = t & 63, wave = t >> 6;
    const int q = lane >> 4, tx = lane & 15;
    const int wm = (wave & 1) * 32, wn = (wave >> 1) * 32;
    const float* xb = x + b * BCN;
    const float* Gb = G + b * 4096;
    f32x4 acc[2][2] = {};
    {   // T[d][nl] = x[(d*12+h)*256 + nn0+nl]  (coalesced rows)
        const int d = t >> 2, fq = t & 3;
        const float* src = xb + (d * HH + h) * NN + nn0;
        #pragma unroll
        for (int u = 0; u < 4; ++u) {
            const int nl = (fq + 4 * u) * 4;
            float4 v = *reinterpret_cast<const float4*>(src + nl);
            T[d][nl + 0] = v.x; T[d][nl + 1] = v.y; T[d][nl + 2] = v.z; T[d][nl + 3] = v.w;
        }
    }
    {   // Bs[dd][d] = cvt(G[dd][d])
        const int r = t >> 2, cq = t & 3;
        const float* src = Gb + r * DD;
        u16* dst = Bs + r * LDP;
        #pragma unroll
        for (int u = 0; u < 4; ++u) {
            const int cl = (cq + 4 * u) * 4;
            float4 v = *reinterpret_cast<const float4*>(src + cl);
            ushort4 w; w.x = f2b(v.x); w.y = f2b(v.y); w.z = f2b(v.z); w.w = f2b(v.w);
            *reinterpret_cast<ushort4*>(dst + cl) = w;
        }
    }
    __syncthreads();
    {   // As[m_local][d] = cvt(T[d][m_local])  (transpose)
        const int nn = t >> 2, dq = t & 3;
        u16* dst = As + nn * LDP;
        #pragma unroll
        for (int u = 0; u < 4; ++u) {
            const int d4 = (dq + 4 * u) * 4;
            ushort4 w;
            w.x = f2b(T[d4 + 0][nn]); w.y = f2b(T[d4 + 1][nn]);
            w.z = f2b(T[d4 + 2][nn]); w.w = f2b(T[d4 + 3][nn]);
            *reinterpret_cast<ushort4*>(dst + d4) = w;
        }
    }
    __syncthreads();
    MFMA8(As, Bs, acc)
    u16* Ub = U + b * BCN;
    #pragma unroll
    for (int i = 0; i < 2; ++i)
        #pragma unroll
        for (int j = 0; j < 2; ++j)
            #pragma unroll
            for (int r = 0; r < 4; ++r) {
                const int m  = m0 + wm + i * 16 + q * 4 + r;
                const int dd = wn + j * 16 + tx;
                Ub[m * DD + dd] = f2b(acc[i][j][r]);
            }
}

// ---------------------------------------------------------------------------
// Stage 4: out[b,o,n] = x[b,o,n] + bd[o] + sum_k Wd[o,k]*U2[n,k]
// A=Wd (f32 cvt), B=U2 = U flat viewed [256][768] (bf16, k-contig). Native NT.
// K=128 per iter (6 iters), 1-deep register prefetch.
// ---------------------------------------------------------------------------
__global__ __launch_bounds__(256) void k_dep(
    const float* __restrict__ Wd, const u16* __restrict__ U,
    const float* __restrict__ bd, const float* __restrict__ x, float* __restrict__ out)
{
    __shared__ __align__(16) u16 As[64 * LDP2];
    __shared__ __align__(16) u16 Bs[64 * LDP2];
    const int n0 = blockIdx.x * 64;
    const int o0 = blockIdx.y * 64;
    const int b  = blockIdx.z;
    const int t = threadIdx.x;
    const int lane = t & 63, wave = t >> 6;
    const int q = lane >> 4, tx = lane & 15;
    const int wm = (wave & 1) * 32, wn = (wave >> 1) * 32;
    const int r4 = t >> 2, cq = t & 3;
    const u16* Ub = U + b * BCN;
    const float* srcA0 = Wd + (o0 + r4) * CC;
    const u16*   srcB0 = Ub + (n0 + r4) * CC;

    float4 ra[8]; uint4 rb[4];
    #pragma unroll
    for (int u = 0; u < 8; ++u)                 // prologue: iter-0 tiles -> regs
        ra[u] = *reinterpret_cast<const float4*>(srcA0 + (cq + 4 * u) * 4);
    #pragma unroll
    for (int u = 0; u < 4; ++u)
        rb[u] = *reinterpret_cast<const uint4*>(srcB0 + ((t & 3) + 4 * u) * 8);

    f32x4 acc[2][2] = {};
    for (int it = 0; it < 6; ++it) {
        if (it > 0) __syncthreads();            // prev MFMA readers done
        {   // regs -> LDS
            u16* dstA = As + r4 * LDP2;
            #pragma unroll
            for (int u = 0; u < 8; ++u) {
                const int cl = (cq + 4 * u) * 4;
                ushort4 w; w.x = f2b(ra[u].x); w.y = f2b(ra[u].y);
                w.z = f2b(ra[u].z); w.w = f2b(ra[u].w);
                *reinterpret_cast<ushort4*>(dstA + cl) = w;
            }
            u16* dstB = Bs + r4 * LDP2;
            #pragma unroll
            for (int u = 0; u < 4; ++u)
                *reinterpret_cast<uint4*>(dstB + ((t & 3) + 4 * u) * 8) = rb[u];
        }
        if (it < 5) {   // next-iter loads in flight across sync + MFMA
            const int c0 = (it + 1) * 128;
            #pragma unroll
            for (int u = 0; u < 8; ++u)
                ra[u] = *reinterpret_cast<const float4*>(srcA0 + c0 + (cq + 4 * u) * 4);
            #pragma unroll
            for (int u = 0; u < 4; ++u)
                rb[u] = *reinterpret_cast<const uint4*>(srcB0 + c0 + ((t & 3) + 4 * u) * 8);
        }
        __syncthreads();
        MFMA16(As, Bs, acc)
    }
    #pragma unroll
    for (int i = 0; i < 2; ++i)
        #pragma unroll
        for (int j = 0; j < 2; ++j)
            #pragma unroll
            for (int r = 0; r < 4; ++r) {
                const int o = o0 + wm + i * 16 + q * 4 + r;
                const int n = n0 + wn + j * 16 + tx;
                const int idx = b * BCN + o * NN + n;
                out[idx] = acc[i][j][r] + bd[o] + x[idx];
            }
}

extern "C" void kernel_launch(void* const* d_in, const int* in_sizes, int n_in,
                              void* d_out, int out_size, void* d_ws, size_t ws_size,
                              hipStream_t stream) {
    const float* x_ori = (const float*)d_in[0];
    const float* cross = (const float*)d_in[1];
    const float* Wp    = (const float*)d_in[2];
    const float* bp    = (const float*)d_in[3];
    const float* Wd    = (const float*)d_in[4];
    const float* bd    = (const float*)d_in[5];
    float* out = (float*)d_out;

    // ws: [0, 3,145,728): cp bf16 [8][768][256]; ALIASED by U bf16
    //     [8][3072][64] after k_gram (cp dead, stream-serialized).
    //     [3,145,728, +131,072): G f32 [8][64][64] (zeroed by k_proj blocks).
    u16*   cp = (u16*)d_ws;
    u16*   U  = (u16*)d_ws;
    float* G  = (float*)((char*)d_ws + (size_t)BB * BCN * sizeof(u16));

    k_proj<<<dim3(4, 12, BB), 256, 0, stream>>>(Wp, cross, bp, cp, G);
    k_gram<<<dim3(24, BB), 256, 0, stream>>>(cross, cp, G);
    k_xm  <<<dim3(48, BB), 256, 0, stream>>>(x_ori, G, U);
    k_dep <<<dim3(4, 12, BB), 256, 0, stream>>>(Wd, U, bd, x_ori, out);
}

// Round 6
// 125.137 us; speedup vs baseline: 1.0485x; 1.0485x over previous
//
#include <hip/hip_runtime.h>

typedef unsigned short u16;
typedef short bf16x8 __attribute__((ext_vector_type(8)));
typedef float f32x4 __attribute__((ext_vector_type(4)));

#define BB 8
#define CC 768
#define NN 256
#define HH 12
#define DD 64
#define K3 3072          // H*N
#define BCN 196608       // C*N per batch
#define SCALE 0.125f
#define LDP 72           // LDS pitch (u16): 144B rows, 16B-aligned, 2-way banks only
#define TP 72            // T pitch (u16)

__device__ __forceinline__ u16 f2b(float f) {
    union { float f; unsigned int i; } v; v.f = f;
    unsigned int r = v.i + 0x7FFFu + ((v.i >> 16) & 1u);
    return (u16)(r >> 16);
}

// one 64x64x64 MFMA macro-step (4 waves, each 32x32, K=64 in two k-halves)
#define MFMA8(ASP, BSP, ACC)                                                              \
    _Pragma("unroll")                                                                     \
    for (int kk = 0; kk < 2; ++kk) {                                                      \
        bf16x8 a0 = *reinterpret_cast<bf16x8*>((ASP) + (wm + tx) * LDP + kk * 32 + q * 8);\
        bf16x8 a1 = *reinterpret_cast<bf16x8*>((ASP) + (wm + 16 + tx) * LDP + kk * 32 + q * 8);\
        bf16x8 b0 = *reinterpret_cast<bf16x8*>((BSP) + (wn + tx) * LDP + kk * 32 + q * 8);\
        bf16x8 b1 = *reinterpret_cast<bf16x8*>((BSP) + (wn + 16 + tx) * LDP + kk * 32 + q * 8);\
        ACC[0][0] = __builtin_amdgcn_mfma_f32_16x16x32_bf16(a0, b0, ACC[0][0], 0, 0, 0);  \
        ACC[0][1] = __builtin_amdgcn_mfma_f32_16x16x32_bf16(a0, b1, ACC[0][1], 0, 0, 0);  \
        ACC[1][0] = __builtin_amdgcn_mfma_f32_16x16x32_bf16(a1, b0, ACC[1][0], 0, 0, 0);  \
        ACC[1][1] = __builtin_amdgcn_mfma_f32_16x16x32_bf16(a1, b1, ACC[1][1], 0, 0, 0);  \
    }

// ---------------------------------------------------------------------------
// Stage 1: cp[b,o,n] = sum_c Wp[o,c]*cross[b,c,n] + bp[o]     (bf16 out)
// K=64 iters, 1-deep register prefetch, FULL double-buffer (As/Bs/T) ->
// 2 barriers/iter (was 3). T stores bf16 (f2b moved from transpose to store:
// bitwise-identical downstream). MFMA(it) overlaps writes+prefetch of it+1.
// Blocks (0,0,b) zero G[b] for k_gram (stream-ordered).
// ---------------------------------------------------------------------------
__global__ __launch_bounds__(256) void k_proj(
    const float* __restrict__ Wp, const float* __restrict__ cross,
    const float* __restrict__ bp, u16* __restrict__ cp, float* __restrict__ G)
{
    __shared__ __align__(16) u16 As[2][64 * LDP];   // 2 x 9216 B
    __shared__ __align__(16) u16 Bs[2][64 * LDP];   // 2 x 9216 B
    __shared__ __align__(16) u16 T [2][64 * TP];    // 2 x 9216 B  (55.3 KB total)
    const int n0 = blockIdx.x * 64;
    const int o0 = blockIdx.y * 64;
    const int b  = blockIdx.z;
    const int t = threadIdx.x;
    const int lane = t & 63, wave = t >> 6;
    const int q = lane >> 4, tx = lane & 15;
    const int wm = (wave & 1) * 32, wn = (wave >> 1) * 32;
    const int r4 = t >> 2, cq = t & 3;

    if (blockIdx.x == 0 && blockIdx.y == 0) {   // zero G[b]
        float4 z = {0.f, 0.f, 0.f, 0.f};
        float* Gb = G + b * 4096;
        #pragma unroll
        for (int j = 0; j < 4; ++j)
            *reinterpret_cast<float4*>(Gb + t * 4 + j * 1024) = z;
    }

    const float* crb = cross + b * BCN;
    const float* wsrc = Wp + (o0 + r4) * CC;    // contiguous row o0+r4

    f32x4 acc[2][2] = {};
    float4 ra[4], rc[4];
    #pragma unroll
    for (int u = 0; u < 4; ++u) {               // prologue: iter-0 tiles -> regs
        const int cl = (cq + 4 * u) * 4;
        ra[u] = *reinterpret_cast<const float4*>(wsrc + cl);
        rc[u] = *reinterpret_cast<const float4*>(crb + r4 * NN + n0 + cl);
    }
    for (int it = 0; it < 12; ++it) {
        const int buf = it & 1;
        {   // regs -> As[buf] (cvt) and T[buf] (cvt)
            u16* dstA = &As[buf][0] + r4 * LDP;
            u16* dstT = &T[buf][0] + r4 * TP;
            #pragma unroll
            for (int u = 0; u < 4; ++u) {
                const int cl = (cq + 4 * u) * 4;
                ushort4 wa; wa.x = f2b(ra[u].x); wa.y = f2b(ra[u].y);
                wa.z = f2b(ra[u].z); wa.w = f2b(ra[u].w);
                *reinterpret_cast<ushort4*>(dstA + cl) = wa;
                ushort4 wt; wt.x = f2b(rc[u].x); wt.y = f2b(rc[u].y);
                wt.z = f2b(rc[u].z); wt.w = f2b(rc[u].w);
                *reinterpret_cast<ushort4*>(dstT + cl) = wt;
            }
        }
        if (it < 11) {   // issue next-iter loads; in flight across transpose+MFMA
            const int c0 = (it + 1) * 64;
            #pragma unroll
            for (int u = 0; u < 4; ++u) {
                const int cl = (cq + 4 * u) * 4;
                ra[u] = *reinterpret_cast<const float4*>(wsrc + c0 + cl);
                rc[u] = *reinterpret_cast<const float4*>(crb + (c0 + r4) * NN + n0 + cl);
            }
        }
        __syncthreads();                        // T[buf]/As[buf] visible
        {   // Bs[buf][n][c] = T[buf][c][n]  (u16 transpose; col reads 2-way = free)
            const int nn = t >> 2, dq = t & 3;
            u16* dst = &Bs[buf][0] + nn * LDP;
            const u16* Tb = &T[buf][0];
            #pragma unroll
            for (int u = 0; u < 4; ++u) {
                const int c4 = (dq + 4 * u) * 4;
                ushort4 w;
                w.x = Tb[(c4 + 0) * TP + nn]; w.y = Tb[(c4 + 1) * TP + nn];
                w.z = Tb[(c4 + 2) * TP + nn]; w.w = Tb[(c4 + 3) * TP + nn];
                *reinterpret_cast<ushort4*>(dst + c4) = w;
            }
        }
        __syncthreads();                        // Bs[buf] visible
        MFMA8((&As[buf][0]), (&Bs[buf][0]), acc)
        // no barrier here: next iter writes buf^1; hazards covered by the two
        // syncs above (any thread's write(it+2) to buf is ordered after
        // sync(it+1)#1, which is after every thread's MFMA(it) via program order)
    }
    u16* cpb = cp + b * BCN;
    #pragma unroll
    for (int i = 0; i < 2; ++i)
        #pragma unroll
        for (int j = 0; j < 2; ++j)
            #pragma unroll
            for (int r = 0; r < 4; ++r) {
                const int o = o0 + wm + i * 16 + q * 4 + r;
                const int n = n0 + wn + j * 16 + tx;
                cpb[o * NN + n] = f2b(acc[i][j][r] + bp[o]);
            }
}

// ---------------------------------------------------------------------------
// Stage 2: G[b][dd][d] += SCALE * sum_k cross_view[dd][k]*cp_view[d][k]
// Split-K 48 x 64 chunks, f32 atomics (G pre-zeroed by k_proj). Unchanged (R4).
// ---------------------------------------------------------------------------
__global__ __launch_bounds__(256) void k_gram(
    const float* __restrict__ cross, const u16* __restrict__ cp, float* __restrict__ G)
{
    __shared__ __align__(16) u16 As[64 * LDP];
    __shared__ __align__(16) u16 Bs[64 * LDP];
    const int kb = blockIdx.x * 64;
    const int b  = blockIdx.y;
    const int t = threadIdx.x;
    const int lane = t & 63, wave = t >> 6;
    const int q = lane >> 4, tx = lane & 15;
    const int wm = (wave & 1) * 32, wn = (wave >> 1) * 32;
    const float* crb = cross + b * BCN;
    const u16* cpb = cp + b * BCN;
    f32x4 acc[2][2] = {};
    {
        const int r = t >> 2, cq = t & 3;
        const float* src = crb + r * K3 + kb;
        u16* dst = As + r * LDP;
        #pragma unroll
        for (int u = 0; u < 4; ++u) {
            const int cl = (cq + 4 * u) * 4;
            float4 v = *reinterpret_cast<const float4*>(src + cl);
            ushort4 w; w.x = f2b(v.x); w.y = f2b(v.y); w.z = f2b(v.z); w.w = f2b(v.w);
            *reinterpret_cast<ushort4*>(dst + cl) = w;
        }
    }
    {
        const int r = t >> 3, ch = (t & 7) * 8;
        *reinterpret_cast<uint4*>(Bs + r * LDP + ch) =
            *reinterpret_cast<const uint4*>(cpb + r * K3 + kb + ch);
        *reinterpret_cast<uint4*>(Bs + (r + 32) * LDP + ch) =
            *reinterpret_cast<const uint4*>(cpb + (r + 32) * K3 + kb + ch);
    }
    __syncthreads();
    MFMA8(As, Bs, acc)
    float* Gb = G + b * 4096;
    #pragma unroll
    for (int i = 0; i < 2; ++i)
        #pragma unroll
        for (int j = 0; j < 2; ++j)
            #pragma unroll
            for (int r = 0; r < 4; ++r) {
                const int dd = wm + i * 16 + q * 4 + r;
                const int d  = wn + j * 16 + tx;
                atomicAdd(Gb + dd * DD + d, acc[i][j][r] * SCALE);
            }
}

// ---------------------------------------------------------------------------
// Stage 3: U[b][m][dd] = sum_d xT[m][d]*G[dd][d].  Unchanged (R4).
// U (bf16) aliases cp. 48 m-tiles x 8 batches.
// ---------------------------------------------------------------------------
__global__ __launch_bounds__(256) void k_xm(
    const float* __restrict__ x, const float* __restrict__ G, u16* __restrict__ U)
{
    __shared__ __align__(16) u16 As[64 * LDP];
    __shared__ __align__(16) u16 Bs[64 * LDP];
    __shared__ __align__(16) float T[64][68];
    const int m0 = blockIdx.x * 64;
    const int b  = blockIdx.y;
    const int h   = m0 >> 8;       // head index (m = h*256 + nn)
    const int nn0 = m0 & 255;
    const int t = threadIdx.x;
    const int lane = t & 63, wave = t >> 6;
    const int q = lane >> 4, tx = lane & 15;
    const int wm = (wave & 1) * 32, wn = (wave >> 1) * 32;
    const float* xb = x + b * BCN;
    const float* Gb = G + b * 4096;
    f32x4 acc[2][2] = {};
    {   // T[d][nl] = x[(d*12+h)*256 + nn0+nl]  (coalesced rows)
        const int d = t >> 2, fq = t & 3;
        const float* src = xb + (d * HH + h) * NN + nn0;
        #pragma unroll
        for (int u = 0; u < 4; ++u) {
            const int nl = (fq + 4 * u) * 4;
            float4 v = *reinterpret_cast<const float4*>(src + nl);
            T[d][nl + 0] = v.x; T[d][nl + 1] = v.y; T[d][nl + 2] = v.z; T[d][nl + 3] = v.w;
        }
    }
    {   // Bs[dd][d] = cvt(G[dd][d])
        const int r = t >> 2, cq = t & 3;
        const float* src = Gb + r * DD;
        u16* dst = Bs + r * LDP;
        #pragma unroll
        for (int u = 0; u < 4; ++u) {
            const int cl = (cq + 4 * u) * 4;
            float4 v = *reinterpret_cast<const float4*>(src + cl);
            ushort4 w; w.x = f2b(v.x); w.y = f2b(v.y); w.z = f2b(v.z); w.w = f2b(v.w);
            *reinterpret_cast<ushort4*>(dst + cl) = w;
        }
    }
    __syncthreads();
    {   // As[m_local][d] = cvt(T[d][m_local])  (transpose)
        const int nn = t >> 2, dq = t & 3;
        u16* dst = As + nn * LDP;
        #pragma unroll
        for (int u = 0; u < 4; ++u) {
            const int d4 = (dq + 4 * u) * 4;
            ushort4 w;
            w.x = f2b(T[d4 + 0][nn]); w.y = f2b(T[d4 + 1][nn]);
            w.z = f2b(T[d4 + 2][nn]); w.w = f2b(T[d4 + 3][nn]);
            *reinterpret_cast<ushort4*>(dst + d4) = w;
        }
    }
    __syncthreads();
    MFMA8(As, Bs, acc)
    u16* Ub = U + b * BCN;
    #pragma unroll
    for (int i = 0; i < 2; ++i)
        #pragma unroll
        for (int j = 0; j < 2; ++j)
            #pragma unroll
            for (int r = 0; r < 4; ++r) {
                const int m  = m0 + wm + i * 16 + q * 4 + r;
                const int dd = wn + j * 16 + tx;
                Ub[m * DD + dd] = f2b(acc[i][j][r]);
            }
}

// ---------------------------------------------------------------------------
// Stage 4: out[b,o,n] = x[b,o,n] + bd[o] + sum_k Wd[o,k]*U2[n,k]
// A=Wd (f32 cvt), B=U2 = U flat viewed [256][768] (bf16, k-contig). Native NT.
// K=64 iters, 1-deep register prefetch, double-buffered LDS -> ONE barrier
// per iter (store(it+2) to buf is ordered after sync(it+1) which is after
// every thread's MFMA(it)).
// ---------------------------------------------------------------------------
__global__ __launch_bounds__(256) void k_dep(
    const float* __restrict__ Wd, const u16* __restrict__ U,
    const float* __restrict__ bd, const float* __restrict__ x, float* __restrict__ out)
{
    __shared__ __align__(16) u16 As[2][64 * LDP];
    __shared__ __align__(16) u16 Bs[2][64 * LDP];
    const int n0 = blockIdx.x * 64;
    const int o0 = blockIdx.y * 64;
    const int b  = blockIdx.z;
    const int t = threadIdx.x;
    const int lane = t & 63, wave = t >> 6;
    const int q = lane >> 4, tx = lane & 15;
    const int wm = (wave & 1) * 32, wn = (wave >> 1) * 32;
    const int r4 = t >> 2, cq = t & 3;
    const int r8 = t >> 3, ch = (t & 7) * 8;
    const u16* Ub = U + b * BCN;
    const float* srcA0 = Wd + (o0 + r4) * CC;

    float4 ra[4]; uint4 rb[2];
    #pragma unroll
    for (int u = 0; u < 4; ++u)                 // prologue: iter-0 tiles -> regs
        ra[u] = *reinterpret_cast<const float4*>(srcA0 + (cq + 4 * u) * 4);
    rb[0] = *reinterpret_cast<const uint4*>(Ub + (n0 + r8) * CC + ch);
    rb[1] = *reinterpret_cast<const uint4*>(Ub + (n0 + r8 + 32) * CC + ch);

    f32x4 acc[2][2] = {};
    for (int it = 0; it < 12; ++it) {
        const int buf = it & 1;
        {   // regs -> LDS[buf]
            u16* dst = &As[buf][0] + r4 * LDP;
            #pragma unroll
            for (int u = 0; u < 4; ++u) {
                const int cl = (cq + 4 * u) * 4;
                ushort4 w; w.x = f2b(ra[u].x); w.y = f2b(ra[u].y);
                w.z = f2b(ra[u].z); w.w = f2b(ra[u].w);
                *reinterpret_cast<ushort4*>(dst + cl) = w;
            }
            *reinterpret_cast<uint4*>(&Bs[buf][0] + r8 * LDP + ch) = rb[0];
            *reinterpret_cast<uint4*>(&Bs[buf][0] + (r8 + 32) * LDP + ch) = rb[1];
        }
        if (it < 11) {   // issue next-iter loads; in flight across sync+MFMA
            const int c0 = (it + 1) * 64;
            #pragma unroll
            for (int u = 0; u < 4; ++u)
                ra[u] = *reinterpret_cast<const float4*>(srcA0 + c0 + (cq + 4 * u) * 4);
            rb[0] = *reinterpret_cast<const uint4*>(Ub + (n0 + r8) * CC + c0 + ch);
            rb[1] = *reinterpret_cast<const uint4*>(Ub + (n0 + r8 + 32) * CC + c0 + ch);
        }
        __syncthreads();                        // LDS[buf] visible
        MFMA8((&As[buf][0]), (&Bs[buf][0]), acc)
        // no second barrier: next store goes to buf^1
    }
    #pragma unroll
    for (int i = 0; i < 2; ++i)
        #pragma unroll
        for (int j = 0; j < 2; ++j)
            #pragma unroll
            for (int r = 0; r < 4; ++r) {
                const int o = o0 + wm + i * 16 + q * 4 + r;
                const int n = n0 + wn + j * 16 + tx;
                const int idx = b * BCN + o * NN + n;
                out[idx] = acc[i][j][r] + bd[o] + x[idx];
            }
}

extern "C" void kernel_launch(void* const* d_in, const int* in_sizes, int n_in,
                              void* d_out, int out_size, void* d_ws, size_t ws_size,
                              hipStream_t stream) {
    const float* x_ori = (const float*)d_in[0];
    const float* cross = (const float*)d_in[1];
    const float* Wp    = (const float*)d_in[2];
    const float* bp    = (const float*)d_in[3];
    const float* Wd    = (const float*)d_in[4];
    const float* bd    = (const float*)d_in[5];
    float* out = (float*)d_out;

    // ws: [0, 3,145,728): cp bf16 [8][768][256]; ALIASED by U bf16
    //     [8][3072][64] after k_gram (cp dead, stream-serialized).
    //     [3,145,728, +131,072): G f32 [8][64][64] (zeroed by k_proj blocks).
    u16*   cp = (u16*)d_ws;
    u16*   U  = (u16*)d_ws;
    float* G  = (float*)((char*)d_ws + (size_t)BB * BCN * sizeof(u16));

    k_proj<<<dim3(4, 12, BB), 256, 0, stream>>>(Wp, cross, bp, cp, G);
    k_gram<<<dim3(48, BB), 256, 0, stream>>>(cross, cp, G);
    k_xm  <<<dim3(48, BB), 256, 0, stream>>>(x_ori, G, U);
    k_dep <<<dim3(4, 12, BB), 256, 0, stream>>>(Wd, U, bd, x_ori, out);
}